// Round 1
// 391.539 us; speedup vs baseline: 1.0988x; 1.0988x over previous
//
#include <hip/hip_runtime.h>

// GCN rank-1 collapse + one-pass counting-sort bucket partition (R8).
// R7 evidence: scatter_sort = 107us at 13.6% HBM / 7.4% VALU / 0 MFMA ->
// latency-serialized, not BW-bound. Prime suspect: 605K per-lane global
// atomicAdds to cursors packed in ~8 cache lines (62 u32 = 4 lines each),
// serializing at L2 per-line RMW rate (~300K cycles ~= whole wall time).
// R8: (1) pad cursors to one 64B line per bucket (CSTR=16); (2) SCH
// 2048->4096 with 512-thread scatter blocks (halves blocks -> halves
// cursor atomics + barriers, doubles flush run length -> less write amp).
// Everything downstream unchanged.

#define TB 256
#define STB 512
#define BSH 13
#define BNODES 8192
#define MAXNB 64
#define SCH 4096
#define SCH4 (SCH / 4)
#define EPT 8
#define CSTR 16
#define INVB 0xFFFFFFFFu

__global__ void init_kernel(unsigned* __restrict__ curD, unsigned* __restrict__ curS,
                            float* __restrict__ Xsum, int NB, unsigned CAP, int G) {
    int i = blockIdx.x * TB + threadIdx.x;
    if (i < NB) { curD[i * CSTR] = (unsigned)i * CAP; curS[i * CSTR] = (unsigned)i * CAP; }
    if (i < G) Xsum[i] = 0.0f;
}

__global__ void scatter_sort_kernel(const int* __restrict__ src, const int* __restrict__ dst,
                                    unsigned* __restrict__ curD, unsigned* __restrict__ curS,
                                    unsigned* __restrict__ dstP, unsigned short* __restrict__ srcP,
                                    int NB, int E) {
    __shared__ unsigned cntD[MAXNB], cntS[MAXNB];     // counts -> insert cursors
    __shared__ unsigned deltaD[MAXNB], deltaS[MAXNB]; // globalBase - localExclusive
    __shared__ unsigned totD_s, totS_s;
    __shared__ unsigned payD[SCH];
    __shared__ unsigned short valS[SCH];
    __shared__ unsigned char mapD[SCH], mapS[SCH];

    int tid = threadIdx.x;
    if (tid < MAXNB) { cntD[tid] = 0u; cntS[tid] = 0u; }
    __syncthreads();

    unsigned sA[EPT], dA[EPT], bD[EPT], bS[EPT];
    int blk = blockIdx.x;
#pragma unroll
    for (int v = 0; v < 2; ++v) {
        int q = blk * SCH4 + v * STB + tid;
        int be = q * 4;
        if (be + 3 < E) {
            int4 s4 = ((const int4*)src)[q];
            int4 d4 = ((const int4*)dst)[q];
            sA[v*4+0] = (unsigned)s4.x; sA[v*4+1] = (unsigned)s4.y;
            sA[v*4+2] = (unsigned)s4.z; sA[v*4+3] = (unsigned)s4.w;
            dA[v*4+0] = (unsigned)d4.x; dA[v*4+1] = (unsigned)d4.y;
            dA[v*4+2] = (unsigned)d4.z; dA[v*4+3] = (unsigned)d4.w;
#pragma unroll
            for (int k = 0; k < 4; ++k) {
                bD[v*4+k] = dA[v*4+k] >> BSH;
                bS[v*4+k] = sA[v*4+k] >> BSH;
            }
        } else {
#pragma unroll
            for (int k = 0; k < 4; ++k) {
                int j = be + k;
                if (j < E) {
                    sA[v*4+k] = (unsigned)src[j];
                    dA[v*4+k] = (unsigned)dst[j];
                    bD[v*4+k] = dA[v*4+k] >> BSH;
                    bS[v*4+k] = sA[v*4+k] >> BSH;
                } else {
                    bD[v*4+k] = INVB; bS[v*4+k] = INVB;
                    sA[v*4+k] = 0u; dA[v*4+k] = 0u;
                }
            }
        }
    }

#pragma unroll
    for (int k = 0; k < EPT; ++k) {
        if (bD[k] != INVB) {
            atomicAdd(&cntD[bD[k]], 1u);
            atomicAdd(&cntS[bS[k]], 1u);
        }
    }
    __syncthreads();

    int wv = tid >> 6, ln = tid & 63;
    if (wv == 0) {
        unsigned x = (ln < NB) ? cntD[ln] : 0u;
        unsigned inc = x;
#pragma unroll
        for (int o = 1; o < 64; o <<= 1) {
            unsigned y = __shfl_up(inc, o, 64);
            if (ln >= o) inc += y;
        }
        unsigned exc = inc - x;
        if (ln < NB) {
            unsigned gb = atomicAdd(&curD[ln * CSTR], x);   // exact reservation, 1 line/bucket
            deltaD[ln] = gb - exc;
            cntD[ln] = exc;                                 // insert cursor
        }
        if (ln == 63) totD_s = inc;
    } else if (wv == 1) {
        unsigned x = (ln < NB) ? cntS[ln] : 0u;
        unsigned inc = x;
#pragma unroll
        for (int o = 1; o < 64; o <<= 1) {
            unsigned y = __shfl_up(inc, o, 64);
            if (ln >= o) inc += y;
        }
        unsigned exc = inc - x;
        if (ln < NB) {
            unsigned gb = atomicAdd(&curS[ln * CSTR], x);
            deltaS[ln] = gb - exc;
            cntS[ln] = exc;
        }
        if (ln == 63) totS_s = inc;
    }
    __syncthreads();

#pragma unroll
    for (int k = 0; k < EPT; ++k) {
        if (bD[k] != INVB) {
            unsigned p = atomicAdd(&cntD[bD[k]], 1u);
            payD[p] = ((dA[k] & (BNODES - 1)) << 19) | sA[k];
            mapD[p] = (unsigned char)bD[k];
            unsigned p2 = atomicAdd(&cntS[bS[k]], 1u);
            valS[p2] = (unsigned short)(sA[k] & (BNODES - 1));
            mapS[p2] = (unsigned char)bS[k];
        }
    }
    __syncthreads();

    unsigned tD = totD_s, tS = totS_s;
    for (unsigned i = tid; i < tD; i += STB) {
        unsigned b = mapD[i];
        dstP[deltaD[b] + i] = payD[i];   // delta[b]+i = gBase + (i - exc[b])
    }
    for (unsigned i = tid; i < tS; i += STB) {
        unsigned b = mapS[i];
        srcP[deltaS[b] + i] = valS[i];
    }
}

// Packed degrees per sub-block: high16 = deg_in (dstP), low16 = deg_out (srcP).
__global__ void deghist_kernel(const unsigned short* __restrict__ srcP, const unsigned* __restrict__ dstP,
                               const unsigned* __restrict__ curS, const unsigned* __restrict__ curD,
                               unsigned CAP, unsigned* __restrict__ pDeg, int Jlg) {
    __shared__ unsigned h[BNODES];
    for (int t = threadIdx.x; t < BNODES; t += TB) h[t] = 0u;
    __syncthreads();
    int b = blockIdx.x >> Jlg;
    int j = blockIdx.x & ((1 << Jlg) - 1);
    unsigned s0 = (unsigned)b * CAP;
    unsigned cD = curD[b * CSTR] - s0;
    unsigned lo = (unsigned)(((unsigned long long)cD * (unsigned)j) >> Jlg);
    unsigned hi = (unsigned)(((unsigned long long)cD * (unsigned)(j + 1)) >> Jlg);
    for (unsigned i = lo + threadIdx.x; i < hi; i += TB)
        atomicAdd(&h[dstP[s0 + i] >> 19], 0x10000u);
    unsigned cS = curS[b * CSTR] - s0;
    lo = (unsigned)(((unsigned long long)cS * (unsigned)j) >> Jlg);
    hi = (unsigned)(((unsigned long long)cS * (unsigned)(j + 1)) >> Jlg);
    for (unsigned i = lo + threadIdx.x; i < hi; i += TB)
        atomicAdd(&h[srcP[s0 + i]], 1u);
    __syncthreads();
    unsigned* row = pDeg + (size_t)blockIdx.x * BNODES;
    for (int t = threadIdx.x; t < BNODES; t += TB) row[t] = h[t];
}

__global__ void prep_kernel(const unsigned* __restrict__ pDeg,
                            float* __restrict__ pio, float* __restrict__ h0s,
                            float* __restrict__ isiA, int Jlg, int Npad) {
    int i = blockIdx.x * TB + threadIdx.x;
    if (i >= Npad) return;
    int b = i >> BSH, l = i & (BNODES - 1);
    int J = 1 << Jlg;
    unsigned sum = 0;
    for (int j = 0; j < J; ++j)
        sum += pDeg[(size_t)((b << Jlg) + j) * BNODES + l];
    float din = (float)(sum >> 16), dout = (float)(sum & 0xFFFFu);
    float a  = 1.0f / sqrtf(fmaxf(din, 1.0f));    // inv_sqrt_in
    float bo = 1.0f / sqrtf(fmaxf(dout, 1.0f));   // inv_sqrt_out
    pio[i]  = a * bo;
    h0s[i]  = din * bo;   // invalid pad nodes: din=0 -> 0, contribute nothing
    isiA[i] = a;
}

// Weighted histogram over dstP: h[dst_local] += table[src].
__global__ void wh_kernel(const unsigned* __restrict__ dstP, const unsigned* __restrict__ curD,
                          unsigned CAP, const float* __restrict__ table,
                          float* __restrict__ pOut, int Jlg) {
    __shared__ float h[BNODES];
    for (int t = threadIdx.x; t < BNODES; t += TB) h[t] = 0.0f;
    __syncthreads();
    int b = blockIdx.x >> Jlg;
    int j = blockIdx.x & ((1 << Jlg) - 1);
    unsigned s0 = (unsigned)b * CAP;
    unsigned cD = curD[b * CSTR] - s0;
    unsigned lo = (unsigned)(((unsigned long long)cD * (unsigned)j) >> Jlg);
    unsigned hi = (unsigned)(((unsigned long long)cD * (unsigned)(j + 1)) >> Jlg);
    for (unsigned i = lo + threadIdx.x; i < hi; i += TB) {
        unsigned e = dstP[s0 + i];
        atomicAdd(&h[e >> 19], table[e & 0x7FFFFu]);
    }
    __syncthreads();
    float* row = pOut + (size_t)blockIdx.x * BNODES;
    for (int t = threadIdx.x; t < BNODES; t += TB) row[t] = h[t];
}

__global__ void mid_kernel(const float* __restrict__ pC, const float* __restrict__ pio,
                           float* __restrict__ sarr, int Jlg, int Npad) {
    int i = blockIdx.x * TB + threadIdx.x;
    if (i >= Npad) return;
    int b = i >> BSH, l = i & (BNODES - 1);
    int J = 1 << Jlg;
    float t1 = 0.0f;
    for (int j = 0; j < J; ++j)
        t1 += pC[(size_t)((b << Jlg) + j) * BNODES + l];
    sarr[i] = t1 * pio[i];
}

__global__ void poolfinal_kernel(const float* __restrict__ pT, const float* __restrict__ isiA,
                                 const int* __restrict__ graph_ids,
                                 float* __restrict__ Xsum, int Jlg, int N) {
    int i = blockIdx.x * TB + threadIdx.x;
    bool valid = i < N;
    int ii = valid ? i : (N - 1);
    int b = ii >> BSH, l = ii & (BNODES - 1);
    int J = 1 << Jlg;
    float t2 = 0.0f;
    for (int j = 0; j < J; ++j)
        t2 += pT[(size_t)((b << Jlg) + j) * BNODES + l];
    float x = valid ? t2 * isiA[ii] : 0.0f;
    int g = graph_ids[ii];
    int g0 = __shfl(g, 0, 64);
    bool uniform = __all((!valid) || (g == g0));
    if (uniform) {
#pragma unroll
        for (int off = 32; off >= 1; off >>= 1) x += __shfl_down(x, off, 64);
        if ((threadIdx.x & 63) == 0) atomicAdd(&Xsum[g0], x);
    } else if (valid) {
        atomicAdd(&Xsum[g], x);
    }
}

__global__ void final_kernel(const float* __restrict__ Xsum, const int* __restrict__ graph_ids,
                             const float* __restrict__ W1, const float* __restrict__ W2,
                             const float* __restrict__ Wlast,
                             float* __restrict__ out, int N, int GC) {
    int i = blockIdx.x * TB + threadIdx.x;
    if (i < GC) {
        int g = i >> 3, j = i & 7;
        int lo = 0, hi = N;
        while (lo < hi) { int m = (lo + hi) >> 1; if (graph_ids[m] < g) lo = m + 1; else hi = m; }
        int lo2 = lo, hi2 = N;
        while (lo2 < hi2) { int m = (lo2 + hi2) >> 1; if (graph_ids[m] < g + 1) lo2 = m + 1; else hi2 = m; }
        float c = (float)(lo2 - lo);
        float r = 0.0f;
#pragma unroll
        for (int cc = 0; cc < 8; ++cc) {
            float m = 0.0f;
#pragma unroll
            for (int k = 0; k < 8; ++k) m += fmaxf(W1[k], 0.0f) * W2[k * 8 + cc];
            r += fmaxf(m, 0.0f) * Wlast[cc * 8 + j];
        }
        out[i] = Xsum[g] / fmaxf(c, 1.0f) * r;
    }
}

// ---------------- fallback (atomic) path ----------------

__global__ void fb_deg_kernel(const int* __restrict__ src, const int* __restrict__ dst,
                              float* __restrict__ deg_out, float* __restrict__ deg_in, int E) {
    int i = blockIdx.x * TB + threadIdx.x;
    if (i < E) {
        atomicAdd(&deg_out[src[i]], 1.0f);
        atomicAdd(&deg_in[dst[i]], 1.0f);
    }
}

__global__ void fb_prep_kernel(const float* __restrict__ deg_in, const float* __restrict__ deg_out,
                               float* __restrict__ isi, float* __restrict__ iso,
                               float* __restrict__ h0s, int N) {
    int i = blockIdx.x * TB + threadIdx.x;
    if (i < N) {
        float di = deg_in[i], dn = deg_out[i];
        float a = 1.0f / sqrtf(fmaxf(di, 1.0f));
        float b = 1.0f / sqrtf(fmaxf(dn, 1.0f));
        isi[i] = a; iso[i] = b; h0s[i] = di * b;
    }
}

__global__ void fb_conv_kernel(const int* __restrict__ src, const int* __restrict__ dst,
                               const float* __restrict__ vals, float* __restrict__ t, int E) {
    int i = blockIdx.x * TB + threadIdx.x;
    if (i < E) atomicAdd(&t[dst[i]], vals[src[i]]);
}

__global__ void fb_mid_kernel(const float* __restrict__ agg1, const float* __restrict__ isi,
                              const float* __restrict__ iso, float* __restrict__ s, int N) {
    int i = blockIdx.x * TB + threadIdx.x;
    if (i < N) s[i] = agg1[i] * isi[i] * iso[i];
}

__global__ void fb_pool_kernel(const float* __restrict__ t2, const float* __restrict__ isi,
                               const int* __restrict__ graph_ids,
                               float* __restrict__ Xsum, float* __restrict__ counts, int N) {
    int i = blockIdx.x * TB + threadIdx.x;
    bool valid = i < N;
    int ii = valid ? i : (N - 1);
    float x = valid ? t2[ii] * isi[ii] : 0.0f;
    float cnt = valid ? 1.0f : 0.0f;
    int g = graph_ids[ii];
    int g0 = __shfl(g, 0, 64);
    bool uniform = __all((!valid) || (g == g0));
    if (uniform) {
#pragma unroll
        for (int off = 32; off >= 1; off >>= 1) {
            x += __shfl_down(x, off, 64);
            cnt += __shfl_down(cnt, off, 64);
        }
        if ((threadIdx.x & 63) == 0) { atomicAdd(&Xsum[g0], x); atomicAdd(&counts[g0], cnt); }
    } else if (valid) {
        atomicAdd(&Xsum[g], x); atomicAdd(&counts[g], 1.0f);
    }
}

__global__ void fb_final_kernel(const float* __restrict__ Xsum, const float* __restrict__ counts,
                                const float* __restrict__ W1, const float* __restrict__ W2,
                                const float* __restrict__ Wlast, float* __restrict__ out, int GC) {
    int i = blockIdx.x * TB + threadIdx.x;
    if (i < GC) {
        int g = i >> 3, j = i & 7;
        float r = 0.0f;
#pragma unroll
        for (int c = 0; c < 8; ++c) {
            float m = 0.0f;
#pragma unroll
            for (int k = 0; k < 8; ++k) m += fmaxf(W1[k], 0.0f) * W2[k * 8 + c];
            r += fmaxf(m, 0.0f) * Wlast[c * 8 + j];
        }
        out[i] = Xsum[g] / fmaxf(counts[g], 1.0f) * r;
    }
}

// ---------------- launch ----------------

extern "C" void kernel_launch(void* const* d_in, const int* in_sizes, int n_in,
                              void* d_out, int out_size, void* d_ws, size_t ws_size,
                              hipStream_t stream) {
    const float* W1        = (const float*)d_in[0];
    const float* W2        = (const float*)d_in[1];
    const float* Wlast     = (const float*)d_in[2];
    const int*   src       = (const int*)d_in[3];
    const int*   dst       = (const int*)d_in[4];
    const int*   graph_ids = (const int*)d_in[5];
    float* out = (float*)d_out;

    const int E = in_sizes[3];
    const int N = in_sizes[5];
    const int G = out_size / 8;

    int NB   = (N + BNODES - 1) >> BSH;
    int Npad = NB << BSH;
    int NCH  = (E + SCH - 1) / SCH;
    // Per-bucket capacity: mean + 8192 (~20 sigma for E=10M random), 512-aligned.
    unsigned CAP = (unsigned)(((E / (NB > 0 ? NB : 1)) + 8192 + 511) & ~511);

    // Pick largest J in {8,4,2,1} whose layout fits ws.
    int Jlg = 3;
    size_t req = 0;
    size_t o_dstP, o_srcP, o_curD, o_curS, o_part, o_pio, o_h0sar, o_isi, o_Xsum;
    for (;; --Jlg) {
        int J = 1 << Jlg;
        size_t off = 0;
        auto A = [&](size_t bytes) { size_t o = off; off = (off + bytes + 127) & ~(size_t)127; return o; };
        o_dstP  = A((size_t)NB * CAP * 4);
        o_srcP  = A((size_t)NB * CAP * 2);
        o_curD  = A((size_t)NB * CSTR * 4);
        o_curS  = A((size_t)NB * CSTR * 4);
        o_part  = A((size_t)NB * J * BNODES * 4);  // pDeg -> pC -> pT (aliased)
        o_pio   = A((size_t)Npad * 4);
        o_h0sar = A((size_t)Npad * 4);             // h0s -> sarr (aliased)
        o_isi   = A((size_t)Npad * 4);
        o_Xsum  = A((size_t)G * 4);
        req = off;
        if (req <= ws_size || Jlg == 0) break;
    }

    bool fast = (N <= (1 << 19)) && (NB <= MAXNB) && (ws_size >= req) && (E >= 1);

    char* bp = (char*)d_ws;

    if (fast) {
        unsigned*       dstP = (unsigned*)(bp + o_dstP);
        unsigned short* srcP = (unsigned short*)(bp + o_srcP);
        unsigned* curD = (unsigned*)(bp + o_curD);
        unsigned* curS = (unsigned*)(bp + o_curS);
        unsigned* pDeg = (unsigned*)(bp + o_part);
        float*    pC   = (float*)(bp + o_part);
        float*    pT   = (float*)(bp + o_part);
        float* pio  = (float*)(bp + o_pio);
        float* h0s  = (float*)(bp + o_h0sar);
        float* sarr = (float*)(bp + o_h0sar);
        float* isiA = (float*)(bp + o_isi);
        float* Xsum = (float*)(bp + o_Xsum);

        int gridNp = (Npad + TB - 1) / TB;
        int gridN  = (N + TB - 1) / TB;
        int J = 1 << Jlg;
        int gridI = (max(NB, G) + TB - 1) / TB;

        init_kernel<<<gridI, TB, 0, stream>>>(curD, curS, Xsum, NB, CAP, G);
        scatter_sort_kernel<<<NCH, STB, 0, stream>>>(src, dst, curD, curS, dstP, srcP, NB, E);
        deghist_kernel<<<NB * J, TB, 0, stream>>>(srcP, dstP, curS, curD, CAP, pDeg, Jlg);
        prep_kernel<<<gridNp, TB, 0, stream>>>(pDeg, pio, h0s, isiA, Jlg, Npad);
        wh_kernel<<<NB * J, TB, 0, stream>>>(dstP, curD, CAP, h0s, pC, Jlg);
        mid_kernel<<<gridNp, TB, 0, stream>>>(pC, pio, sarr, Jlg, Npad);
        wh_kernel<<<NB * J, TB, 0, stream>>>(dstP, curD, CAP, sarr, pT, Jlg);
        poolfinal_kernel<<<gridN, TB, 0, stream>>>(pT, isiA, graph_ids, Xsum, Jlg, N);
        final_kernel<<<(out_size + TB - 1) / TB, TB, 0, stream>>>(Xsum, graph_ids,
                                                                  W1, W2, Wlast, out, N, out_size);
    } else {
        float* ws = (float*)d_ws;
        size_t f = 0;
        auto FA = [&](size_t n) { size_t o = f; f += (n + 3) & ~(size_t)3; return o; };
        size_t f_degin  = FA(N);
        size_t f_degout = FA(N);
        size_t f_agg1   = FA(N);
        size_t f_t2     = FA(N);
        size_t f_Xsum   = FA(G);
        size_t f_cnt    = FA(G);
        size_t zf = f;
        size_t f_isi = FA(N);
        size_t f_iso = FA(N);
        size_t f_h0s = FA(N);
        size_t f_s   = FA(N);
        hipMemsetAsync(ws, 0, zf * sizeof(float), stream);
        int gridE = (E + TB - 1) / TB;
        int gridN = (N + TB - 1) / TB;
        int gridO = (out_size + TB - 1) / TB;
        fb_deg_kernel<<<gridE, TB, 0, stream>>>(src, dst, ws + f_degout, ws + f_degin, E);
        fb_prep_kernel<<<gridN, TB, 0, stream>>>(ws + f_degin, ws + f_degout,
                                                 ws + f_isi, ws + f_iso, ws + f_h0s, N);
        fb_conv_kernel<<<gridE, TB, 0, stream>>>(src, dst, ws + f_h0s, ws + f_agg1, E);
        fb_mid_kernel<<<gridN, TB, 0, stream>>>(ws + f_agg1, ws + f_isi, ws + f_iso, ws + f_s, N);
        fb_conv_kernel<<<gridE, TB, 0, stream>>>(src, dst, ws + f_s, ws + f_t2, E);
        fb_pool_kernel<<<gridN, TB, 0, stream>>>(ws + f_t2, ws + f_isi, graph_ids,
                                                 ws + f_Xsum, ws + f_cnt, N);
        fb_final_kernel<<<gridO, TB, 0, stream>>>(ws + f_Xsum, ws + f_cnt, W1, W2, Wlast,
                                                  out, out_size);
    }
}